// Round 1
// baseline (283.421 us; speedup 1.0000x reference)
//
// NeuralExecutor2 — r9: grand fusion. One cooperative kernel (512 blocks x 256 thr),
// grid.sync() at the two cross-block dependency points (B1 ready; B2/hp2 ready).
// drv recomputed per block; adj/ef staged to LDS once; z/A1/A2/nh/hp1 stay in LDS.
#include <hip/hip_runtime.h>
#include <hip/hip_cooperative_groups.h>

namespace cg = cooperative_groups;

#define XN 512
#define XB 4
#define XSENT (-1.0e30f)          // finite sentinel for masked p entries
#define XNEG (-3.402823466e38f)   // -FLT_MAX init for max reductions

__device__ __forceinline__ float xscrub(float v) {
    unsigned u = __float_as_uint(v);
    u = ((u & 0x7f800000u) == 0x7f800000u) ? 0xff7fffffu : u;  // inf/nan -> -FLT_MAX bits
    return __uint_as_float(u);
}

__global__ __launch_bounds__(256, 2) void ne2z_fused(
    const float* __restrict__ x, const float* __restrict__ h,
    const int* __restrict__ adj, const float* __restrict__ ef,
    const float* __restrict__ Wn, const float* __restrict__ We,
    const float* __restrict__ Wm, const float* __restrict__ Wu,
    const float* __restrict__ Wtm, const float* __restrict__ Wtu,
    const float* __restrict__ Wd, const float* __restrict__ Wt,
    const float* __restrict__ Wp,
    float* __restrict__ B1, float* __restrict__ B2, float* __restrict__ hp2,
    float* __restrict__ o_newx, float* __restrict__ o_p,
    float* __restrict__ o_tau, float* __restrict__ o_newh)
{
    const int q = blockIdx.x;                 // 0..511
    const int b = q >> 7;                     // 128 blocks per batch
    const int i0 = (q & 127) * 4;
    const int row0 = b * XN + i0;
    const int t = threadIdx.x;

    __shared__ float ev[4][XN];               // 8 KB, lives whole kernel
    __shared__ int   mk[4][XN];               // 8 KB, lives whole kernel
    __shared__ float c1s[32], c2s[32], u1s[32], u2s[32];
    __shared__ float cps;
    __shared__ float zs[4][32], a1s[4][32], ag[4][32], nh[4][32], a2s[4][32];
    __shared__ float red[4][8][33];
    __shared__ float hp1s[4];
    __shared__ float ss[4][32];

    // ---- stage adjacency/edge rows for this block's 4 i-rows (once, reused 3x) ----
    {
        const int*   ab = adj + (size_t)row0 * XN;   // 4 rows contiguous
        const float* eb = ef  + (size_t)row0 * XN;
        for (int u = t; u < 4 * XN; u += 256) {
            const int r = u >> 9, j = u & (XN - 1);
            ev[r][j] = eb[u];
            mk[r][j] = (ab[u] != 0) | (j == i0 + r);
        }
    }

    // ---- derived vectors (redundant per block; replaces g0) ----
    if (t < 32) {
        float c1 = 0.f, c2 = 0.f;
        for (int k = 0; k < 32; ++k) {
            const float w = We[k];
            c1 += w * Wm[(64 + k) * 32 + t];
            c2 += w * Wtm[(64 + k) * 32 + t];
        }
        c1s[t] = c1;
        c2s[t] = c2;
        float u1 = 0.f, u2 = 0.f;
        for (int k = 0; k < 32; ++k) {
            u1 += Wtu[t * 32 + k]        * Wt[k];
            u2 += Wtu[(32 + k) * 32 + t == 0 ? (32 + t) * 32 + k : (32 + t) * 32 + k] * Wt[k];
        }
        u1s[t] = u1;
        u2s[t] = u2;
        if (t == 0) {
            float cp = 0.f;
            for (int k = 0; k < 32; ++k) cp += We[k] * Wp[64 + k];
            cps = cp;
        }
    }
    if (q == 0 && t < XB) o_tau[t] = 0.f;     // tau zero, before first grid sync

    // ---- phase 1 (g1): z = [x,h]@Wn ; A1 local ; B1 -> global ----
    if (t < 128) {
        const int r = t >> 5, l = t & 31;
        const int row = row0 + r;
        float acc = 0.f;
        const float* xr = x + row * 3;
        const float* hr = h + row * 32;
        for (int k = 0; k < 3; ++k)  acc += xr[k] * Wn[k * 32 + l];
        for (int k = 0; k < 32; ++k) acc += hr[k] * Wn[(3 + k) * 32 + l];
        zs[r][l] = acc;
    }
    __syncthreads();
    if (t < 128) {
        const int r = t >> 5, l = t & 31;
        float a = 0.f, bb = 0.f;
        for (int k = 0; k < 32; ++k) {
            const float zk = zs[r][k];
            a  += zk * Wm[k * 32 + l];
            bb += zk * Wm[(32 + k) * 32 + l];
        }
        a1s[r][l] = a;
        B1[(row0 + r) * 32 + l] = bb;
    }

    __threadfence();
    cg::this_grid().sync();                   // B1 visible grid-wide

    // ---- phase 2 (m2): mpnn1 scan over all j ----
    {
        const int c = t >> 5, l = t & 31;
        const float c1 = c1s[l];
        const float* B1b = B1 + (size_t)b * XN * 32;
        float m0 = XNEG, m1 = XNEG, m2v = XNEG, m3v = XNEG;
#pragma unroll 4
        for (int k = 0; k < 64; ++k) {
            const int j = c * 64 + k;
            const float bv = B1b[j * 32 + l];
            float v0 = bv + ev[0][j] * c1;  m0  = fmaxf(m0,  mk[0][j] ? v0 : XNEG);
            float v1 = bv + ev[1][j] * c1;  m1  = fmaxf(m1,  mk[1][j] ? v1 : XNEG);
            float v2 = bv + ev[2][j] * c1;  m2v = fmaxf(m2v, mk[2][j] ? v2 : XNEG);
            float v3 = bv + ev[3][j] * c1;  m3v = fmaxf(m3v, mk[3][j] ? v3 : XNEG);
        }
        red[0][c][l] = m0;  red[1][c][l] = m1;
        red[2][c][l] = m2v; red[3][c][l] = m3v;
    }
    __syncthreads();
    if (t < 128) {
        const int r = t >> 5, ll = t & 31;
        float mm = red[r][0][ll];
        for (int cc = 1; cc < 8; ++cc) mm = fmaxf(mm, red[r][cc][ll]);
        ag[r][ll] = a1s[r][ll] + mm;
    }
    __syncthreads();
    if (t < 128) {
        const int r = t >> 5, ll = t & 31;
        float v = zs[r][ll];                  // residual + z
        for (int k = 0; k < 32; ++k)
            v += zs[r][k] * Wu[k * 32 + ll] + ag[r][k] * Wu[(32 + k) * 32 + ll];
        nh[r][ll] = v;
        o_newh[(row0 + r) * 32 + ll] = v;
    }
    __syncthreads();
    if (t < 128) {
        const int r = t >> 5, ll = t & 31;
        float a2 = 0.f, b2 = 0.f;
        for (int k = 0; k < 32; ++k) {
            const float nk = nh[r][k];
            a2 += nk * Wtm[k * 32 + ll];
            b2 += nk * Wtm[(32 + k) * 32 + ll];
        }
        a2s[r][ll] = a2;
        B2[(row0 + r) * 32 + ll] = b2;
    } else if (t < 136) {                     // 8 threads: 4 rows x {hp1,hp2}
        const int r = (t - 128) >> 1, which = (t - 128) & 1;
        float p = 0.f;
        for (int k = 0; k < 32; ++k) p += nh[r][k] * Wp[which * 32 + k];
        if (which) hp2[row0 + r] = p;
        else       hp1s[r] = p;
    } else if (t >= 160 && t < 172) {         // 12 threads: 4 rows x 3 cols
        const int r = (t - 160) / 3, d = (t - 160) % 3;
        float v = 0.f;
        for (int k = 0; k < 32; ++k)
            v += zs[r][k] * Wd[k * 3 + d] + nh[r][k] * Wd[(32 + k) * 3 + d];
        o_newx[(row0 + r) * 3 + d] = v;
    }

    __threadfence();
    cg::this_grid().sync();                   // B2 / hp2 visible grid-wide

    // ---- phase 3 (m3): fused p-head + termination scan + tau ----
    {
        const float cp = cps;
        const float* h2 = hp2 + b * XN;
#pragma unroll
        for (int r = 0; r < 4; ++r) {
            const float h1 = hp1s[r];
            float* pr = o_p + (size_t)(row0 + r) * XN;
            for (int j = t; j < XN; j += 256) {
                const float v = mk[r][j] ? (h1 + h2[j] + ev[r][j] * cp) : XSENT;
                pr[j] = xscrub(v);
            }
        }
    }
    {
        const int c = t >> 5, l = t & 31;
        const float c2 = c2s[l];
        const float* B2b = B2 + (size_t)b * XN * 32;
        float m0 = XNEG, m1 = XNEG, m2v = XNEG, m3v = XNEG;
#pragma unroll 4
        for (int k = 0; k < 64; ++k) {
            const int j = c * 64 + k;
            const float bv = B2b[j * 32 + l];
            float v0 = bv + ev[0][j] * c2;  m0  = fmaxf(m0,  mk[0][j] ? v0 : XNEG);
            float v1 = bv + ev[1][j] * c2;  m1  = fmaxf(m1,  mk[1][j] ? v1 : XNEG);
            float v2 = bv + ev[2][j] * c2;  m2v = fmaxf(m2v, mk[2][j] ? v2 : XNEG);
            float v3 = bv + ev[3][j] * c2;  m3v = fmaxf(m3v, mk[3][j] ? v3 : XNEG);
        }
        red[0][c][l] = m0;  red[1][c][l] = m1;
        red[2][c][l] = m2v; red[3][c][l] = m3v;
    }
    __syncthreads();
    if (t < 128) {
        const int r = t >> 5, ll = t & 31;
        float mm = red[r][0][ll];
        for (int cc = 1; cc < 8; ++cc) mm = fmaxf(mm, red[r][cc][ll]);
        const float agg = a2s[r][ll] + mm;
        ss[r][ll] = nh[r][ll] * u1s[ll] + agg * u2s[ll];
    }
    __syncthreads();
    if (t == 0) {
        float s = 0.f;
        for (int r = 0; r < 4; ++r)
            for (int k = 0; k < 32; ++k) s += ss[r][k];
        atomicAdd(&o_tau[b], s * (1.0f / XN));
    }
}

extern "C" void kernel_launch(void* const* d_in, const int* in_sizes, int n_in,
                              void* d_out, int out_size, void* d_ws, size_t ws_size,
                              hipStream_t stream)
{
    const float* x   = (const float*)d_in[0];
    const float* h   = (const float*)d_in[1];
    const int*   adj = (const int*)  d_in[2];
    const float* ef  = (const float*)d_in[3];
    const float* Wn  = (const float*)d_in[4];
    const float* We  = (const float*)d_in[5];
    const float* Wm  = (const float*)d_in[6];
    const float* Wu  = (const float*)d_in[7];
    const float* Wtm = (const float*)d_in[8];
    const float* Wtu = (const float*)d_in[9];
    const float* Wd  = (const float*)d_in[10];
    const float* Wt  = (const float*)d_in[11];
    const float* Wp  = (const float*)d_in[12];

    float* out    = (float*)d_out;
    float* o_newx = out;                          // [4,512,3]   6144
    float* o_p    = out + 6144;                   // [4,512,512] 1048576
    float* o_tau  = out + 6144 + XB * XN * XN;    // [4,1]       4
    float* o_newh = o_tau + XB;                   // [4,512,32]  65536

    float* w = (float*)d_ws;
    const int RN = XB * XN * 32;                  // 65536
    float* B1  = w;
    float* B2  = w + RN;
    float* hp2 = w + 2 * RN;

    void* args[] = {
        (void*)&x, (void*)&h, (void*)&adj, (void*)&ef,
        (void*)&Wn, (void*)&We, (void*)&Wm, (void*)&Wu,
        (void*)&Wtm, (void*)&Wtu, (void*)&Wd, (void*)&Wt, (void*)&Wp,
        (void*)&B1, (void*)&B2, (void*)&hp2,
        (void*)&o_newx, (void*)&o_p, (void*)&o_tau, (void*)&o_newh
    };
    hipLaunchCooperativeKernel((const void*)ne2z_fused,
                               dim3(XB * XN / 4), dim3(256), args, 0, stream);
}

// Round 3
// 111.255 us; speedup vs baseline: 2.5475x; 2.5475x over previous
//
// NeuralExecutor2 — r10b: resubmit of r10 (round-2 bench was an infra failure, not a kernel error).
// Kernel-boundary pipeline, 3 dispatches. g0 folded into g1; NaN-poison mask folded into ev at
// staging (scan inner loop = fma+fmax only, mk[] LDS dropped); int4/float4 staging; parallel tau.
#include <hip/hip_runtime.h>

#define XN 512
#define XB 4
#define XSENT (-1.0e30f)          // finite sentinel for masked p entries
#define XNEG (-3.402823466e38f)   // -FLT_MAX init for max reductions
#define QNANU 0x7fc00000u

// ---- g1: drv + tau-zero (block 0) ; z = [x,h]@Wn ; A1 = z@Wm[0:32] ; B1 = z@Wm[32:64] ----
__global__ __launch_bounds__(256) void ne2r_g1(
    const float* __restrict__ x, const float* __restrict__ h,
    const float* __restrict__ Wn, const float* __restrict__ Wm,
    const float* __restrict__ We, const float* __restrict__ Wtm,
    const float* __restrict__ Wtu, const float* __restrict__ Wt,
    const float* __restrict__ Wp,
    float* __restrict__ z, float* __restrict__ A1, float* __restrict__ B1,
    float* __restrict__ drv, float* __restrict__ tau_out)
{
    const int t = threadIdx.x;
    if (blockIdx.x == 0) {                    // fused g0: derived vectors + tau zero
        if (t < 32) {
            float c1 = 0.f, c2 = 0.f;
            for (int k = 0; k < 32; ++k) {
                const float w = We[k];
                c1 += w * Wm[(64 + k) * 32 + t];
                c2 += w * Wtm[(64 + k) * 32 + t];
            }
            drv[t]      = c1;
            drv[32 + t] = c2;
            float u1 = 0.f, u2 = 0.f;
            for (int k = 0; k < 32; ++k) {
                u1 += Wtu[t * 32 + k]        * Wt[k];
                u2 += Wtu[(32 + t) * 32 + k] * Wt[k];
            }
            drv[64 + t] = u1;
            drv[96 + t] = u2;
            if (t == 0) {
                float cp = 0.f;
                for (int k = 0; k < 32; ++k) cp += We[k] * Wp[64 + k];
                drv[128] = cp;
            }
        } else if (t >= 64 && t < 64 + XB) {
            tau_out[t - 64] = 0.f;
        }
    }
    const int r = t >> 5;
    const int l = t & 31;
    const int row = blockIdx.x * 8 + r;
    float acc = 0.f;
    {
        const float* xr = x + row * 3;
        const float* hr = h + row * 32;
        for (int k = 0; k < 3; ++k)  acc += xr[k] * Wn[k * 32 + l];
        for (int k = 0; k < 32; ++k) acc += hr[k] * Wn[(3 + k) * 32 + l];
    }
    __shared__ float zs[8][32];
    zs[r][l] = acc;
    z[row * 32 + l] = acc;
    __syncthreads();
    float a = 0.f, bb = 0.f;
    for (int k = 0; k < 32; ++k) {
        const float zk = zs[r][k];
        a  += zk * Wm[k * 32 + l];
        bb += zk * Wm[(32 + k) * 32 + l];
    }
    A1[row * 32 + l] = a;
    B1[row * 32 + l] = bb;
}

// ---- m2: mpnn1 — 4 i-rows per block share the B1 j-scan; NaN-masked ev ----
__global__ __launch_bounds__(256) void ne2r_m2(
    const int* __restrict__ adj, const float* __restrict__ ef,
    const float* __restrict__ z, const float* __restrict__ A1,
    const float* __restrict__ B1, const float* __restrict__ drv,
    const float* __restrict__ Wu, const float* __restrict__ Wd,
    const float* __restrict__ Wtm, const float* __restrict__ Wp,
    float* __restrict__ A2, float* __restrict__ B2,
    float* __restrict__ hp1, float* __restrict__ hp2,
    float* __restrict__ o_newx, float* __restrict__ o_newh)
{
    const int q = blockIdx.x;                 // 0..511
    const int b = q >> 7;                     // 128 blocks per batch
    const int i0 = (q & 127) * 4;
    const int row0 = b * XN + i0;
    const int t = threadIdx.x;
    const float qnan = __uint_as_float(QNANU);

    __shared__ float ev[4][XN];               // masked: qNaN where !adj && !self
    {
        const int4*   ab4 = (const int4*)  (adj + (size_t)row0 * XN);
        const float4* eb4 = (const float4*)(ef  + (size_t)row0 * XN);
        for (int u = t; u < XN; u += 256) {   // 512 vec4 chunks cover 4 rows
            const int4   a4 = ab4[u];
            const float4 e4 = eb4[u];
            const int r  = u >> 7;
            const int j0 = (u & 127) << 2;
            const int self = i0 + r;
            ev[r][j0 + 0] = (a4.x || (j0 + 0) == self) ? e4.x : qnan;
            ev[r][j0 + 1] = (a4.y || (j0 + 1) == self) ? e4.y : qnan;
            ev[r][j0 + 2] = (a4.z || (j0 + 2) == self) ? e4.z : qnan;
            ev[r][j0 + 3] = (a4.w || (j0 + 3) == self) ? e4.w : qnan;
        }
    }
    __syncthreads();

    const int c = t >> 5, l = t & 31;
    const float c1 = drv[l];
    const float* B1b = B1 + (size_t)b * XN * 32;
    float m0 = XNEG, m1 = XNEG, m2v = XNEG, m3v = XNEG;
#pragma unroll 4
    for (int k = 0; k < 64; ++k) {
        const int j = c * 64 + k;
        const float bv = B1b[j * 32 + l];
        // masked ev is NaN -> fma yields NaN -> fmaxf returns old m (IEEE maxNum)
        m0  = fmaxf(m0,  fmaf(ev[0][j], c1, bv));
        m1  = fmaxf(m1,  fmaf(ev[1][j], c1, bv));
        m2v = fmaxf(m2v, fmaf(ev[2][j], c1, bv));
        m3v = fmaxf(m3v, fmaf(ev[3][j], c1, bv));
    }
    __shared__ float red[4][8][33];
    red[0][c][l] = m0;  red[1][c][l] = m1;
    red[2][c][l] = m2v; red[3][c][l] = m3v;
    __syncthreads();

    __shared__ float zs[4][32], ag[4][32], nh[4][32];
    if (t < 128) {
        const int r = t >> 5, ll = t & 31;
        float mm = red[r][0][ll];
        for (int cc = 1; cc < 8; ++cc) mm = fmaxf(mm, red[r][cc][ll]);
        ag[r][ll] = A1[(row0 + r) * 32 + ll] + mm;
        zs[r][ll] = z[(row0 + r) * 32 + ll];
    }
    __syncthreads();
    if (t < 128) {
        const int r = t >> 5, ll = t & 31;
        float v = zs[r][ll];                              // residual + z
        for (int k = 0; k < 32; ++k)
            v += zs[r][k] * Wu[k * 32 + ll] + ag[r][k] * Wu[(32 + k) * 32 + ll];
        nh[r][ll] = v;
        o_newh[(row0 + r) * 32 + ll] = v;
    }
    __syncthreads();
    if (t < 128) {
        const int r = t >> 5, ll = t & 31;
        float a2 = 0.f, b2 = 0.f;
        for (int k = 0; k < 32; ++k) {
            const float nk = nh[r][k];
            a2 += nk * Wtm[k * 32 + ll];
            b2 += nk * Wtm[(32 + k) * 32 + ll];
        }
        A2[(row0 + r) * 32 + ll] = a2;
        B2[(row0 + r) * 32 + ll] = b2;
    } else if (t < 136) {                                 // 8 threads: 4 rows x {hp1,hp2}
        const int r = (t - 128) >> 1, which = (t - 128) & 1;
        float p = 0.f;
        for (int k = 0; k < 32; ++k) p += nh[r][k] * Wp[which * 32 + k];
        (which ? hp2 : hp1)[row0 + r] = p;
    } else if (t >= 160 && t < 172) {                     // 12 threads: 4 rows x 3 cols
        const int r = (t - 160) / 3, d = (t - 160) % 3;
        float v = 0.f;
        for (int k = 0; k < 32; ++k)
            v += zs[r][k] * Wd[k * 3 + d] + nh[r][k] * Wd[(32 + k) * 3 + d];
        o_newx[(row0 + r) * 3 + d] = v;
    }
}

// ---- m3: termination scan (4 rows/block) + fused p-head + tau ----
__global__ __launch_bounds__(256) void ne2r_m3(
    const int* __restrict__ adj, const float* __restrict__ ef,
    const float* __restrict__ A2, const float* __restrict__ B2,
    const float* __restrict__ newh, const float* __restrict__ hp1,
    const float* __restrict__ hp2, const float* __restrict__ drv,
    float* __restrict__ o_p, float* __restrict__ tau_out)
{
    const int q = blockIdx.x;
    const int b = q >> 7;
    const int i0 = (q & 127) * 4;
    const int row0 = b * XN + i0;
    const int t = threadIdx.x;
    const float qnan = __uint_as_float(QNANU);

    __shared__ float ev[4][XN];               // masked: qNaN where !adj && !self
    {
        const int4*   ab4 = (const int4*)  (adj + (size_t)row0 * XN);
        const float4* eb4 = (const float4*)(ef  + (size_t)row0 * XN);
        for (int u = t; u < XN; u += 256) {
            const int4   a4 = ab4[u];
            const float4 e4 = eb4[u];
            const int r  = u >> 7;
            const int j0 = (u & 127) << 2;
            const int self = i0 + r;
            ev[r][j0 + 0] = (a4.x || (j0 + 0) == self) ? e4.x : qnan;
            ev[r][j0 + 1] = (a4.y || (j0 + 1) == self) ? e4.y : qnan;
            ev[r][j0 + 2] = (a4.z || (j0 + 2) == self) ? e4.z : qnan;
            ev[r][j0 + 3] = (a4.w || (j0 + 3) == self) ? e4.w : qnan;
        }
    }
    __syncthreads();

    // fused predecessor head: masked entries show up as NaN -> map to sentinel (bit test,
    // fast-math-proof). Unmasked values are provably finite -> pass through unchanged.
    {
        const float cp = drv[128];
        const float* h2 = hp2 + b * XN;
#pragma unroll
        for (int r = 0; r < 4; ++r) {
            const float h1 = hp1[row0 + r];
            float* pr = o_p + (size_t)(row0 + r) * XN;
            for (int j = t; j < XN; j += 256) {
                const float pv = fmaf(ev[r][j], cp, h1 + h2[j]);
                const unsigned bv = __float_as_uint(pv);
                pr[j] = ((bv & 0x7f800000u) == 0x7f800000u) ? XSENT : pv;
            }
        }
    }

    const int c = t >> 5, l = t & 31;
    const float c2 = drv[32 + l];
    const float* B2b = B2 + (size_t)b * XN * 32;
    float m0 = XNEG, m1 = XNEG, m2v = XNEG, m3v = XNEG;
#pragma unroll 4
    for (int k = 0; k < 64; ++k) {
        const int j = c * 64 + k;
        const float bv = B2b[j * 32 + l];
        m0  = fmaxf(m0,  fmaf(ev[0][j], c2, bv));
        m1  = fmaxf(m1,  fmaf(ev[1][j], c2, bv));
        m2v = fmaxf(m2v, fmaf(ev[2][j], c2, bv));
        m3v = fmaxf(m3v, fmaf(ev[3][j], c2, bv));
    }
    __shared__ float red[4][8][33];
    red[0][c][l] = m0;  red[1][c][l] = m1;
    red[2][c][l] = m2v; red[3][c][l] = m3v;
    __syncthreads();

    __shared__ float ss[4][32];
    if (t < 128) {
        const int r = t >> 5, ll = t & 31;
        float mm = red[r][0][ll];
        for (int cc = 1; cc < 8; ++cc) mm = fmaxf(mm, red[r][cc][ll]);
        const float agg = A2[(row0 + r) * 32 + ll] + mm;
        ss[r][ll] = newh[(row0 + r) * 32 + ll] * drv[64 + ll] + agg * drv[96 + ll];
    }
    __syncthreads();
    if (t < 64) {                              // parallel tau reduce (one wave)
        const float* ssf = &ss[0][0];
        float s = ssf[t] + ssf[t + 64];
#pragma unroll
        for (int o = 32; o > 0; o >>= 1) s += __shfl_down(s, o);
        if (t == 0) atomicAdd(&tau_out[b], s * (1.0f / XN));
    }
}

extern "C" void kernel_launch(void* const* d_in, const int* in_sizes, int n_in,
                              void* d_out, int out_size, void* d_ws, size_t ws_size,
                              hipStream_t stream)
{
    const float* x   = (const float*)d_in[0];
    const float* h   = (const float*)d_in[1];
    const int*   adj = (const int*)  d_in[2];
    const float* ef  = (const float*)d_in[3];
    const float* Wn  = (const float*)d_in[4];
    const float* We  = (const float*)d_in[5];
    const float* Wm  = (const float*)d_in[6];
    const float* Wu  = (const float*)d_in[7];
    const float* Wtm = (const float*)d_in[8];
    const float* Wtu = (const float*)d_in[9];
    const float* Wd  = (const float*)d_in[10];
    const float* Wt  = (const float*)d_in[11];
    const float* Wp  = (const float*)d_in[12];

    float* out    = (float*)d_out;
    float* o_newx = out;                          // [4,512,3]   6144
    float* o_p    = out + 6144;                   // [4,512,512] 1048576
    float* o_tau  = out + 6144 + XB * XN * XN;    // [4,1]       4
    float* o_newh = o_tau + XB;                   // [4,512,32]  65536

    float* w = (float*)d_ws;
    const int RN = XB * XN * 32;                  // 65536
    float* z   = w;
    float* A1  = w + RN;
    float* B1  = w + 2 * RN;
    float* A2  = w + 3 * RN;
    float* B2  = w + 4 * RN;
    float* hp1 = w + 5 * RN;
    float* hp2 = w + 5 * RN + XB * XN;
    float* drv = w + 5 * RN + 2 * XB * XN;

    hipLaunchKernelGGL(ne2r_g1, dim3(XB * XN / 8), dim3(256), 0, stream,
                       x, h, Wn, Wm, We, Wtm, Wtu, Wt, Wp, z, A1, B1, drv, o_tau);
    hipLaunchKernelGGL(ne2r_m2, dim3(XB * XN / 4), dim3(256), 0, stream,
                       adj, ef, z, A1, B1, drv, Wu, Wd, Wtm, Wp,
                       A2, B2, hp1, hp2, o_newx, o_newh);
    hipLaunchKernelGGL(ne2r_m3, dim3(XB * XN / 4), dim3(256), 0, stream,
                       adj, ef, A2, B2, o_newh, hp1, hp2, drv, o_p, o_tau);
}

// Round 4
// 105.268 us; speedup vs baseline: 2.6924x; 1.0569x over previous
//
// NeuralExecutor2 — r11: r10b + float4 LDS ev path in both scans (ds_read_b128 broadcast,
// 256 b32 -> 64 b128 per thread; float4 staging writes). DS-issue was ~5us/kernel by cycle model.
#include <hip/hip_runtime.h>

#define XN 512
#define XB 4
#define XSENT (-1.0e30f)          // finite sentinel for masked p entries
#define XNEG (-3.402823466e38f)   // -FLT_MAX init for max reductions
#define QNANU 0x7fc00000u

// ---- g1: drv + tau-zero (block 0) ; z = [x,h]@Wn ; A1 = z@Wm[0:32] ; B1 = z@Wm[32:64] ----
__global__ __launch_bounds__(256) void ne2s_g1(
    const float* __restrict__ x, const float* __restrict__ h,
    const float* __restrict__ Wn, const float* __restrict__ Wm,
    const float* __restrict__ We, const float* __restrict__ Wtm,
    const float* __restrict__ Wtu, const float* __restrict__ Wt,
    const float* __restrict__ Wp,
    float* __restrict__ z, float* __restrict__ A1, float* __restrict__ B1,
    float* __restrict__ drv, float* __restrict__ tau_out)
{
    const int t = threadIdx.x;
    if (blockIdx.x == 0) {                    // fused g0: derived vectors + tau zero
        if (t < 32) {
            float c1 = 0.f, c2 = 0.f;
            for (int k = 0; k < 32; ++k) {
                const float w = We[k];
                c1 += w * Wm[(64 + k) * 32 + t];
                c2 += w * Wtm[(64 + k) * 32 + t];
            }
            drv[t]      = c1;
            drv[32 + t] = c2;
            float u1 = 0.f, u2 = 0.f;
            for (int k = 0; k < 32; ++k) {
                u1 += Wtu[t * 32 + k]        * Wt[k];
                u2 += Wtu[(32 + t) * 32 + k] * Wt[k];
            }
            drv[64 + t] = u1;
            drv[96 + t] = u2;
            if (t == 0) {
                float cp = 0.f;
                for (int k = 0; k < 32; ++k) cp += We[k] * Wp[64 + k];
                drv[128] = cp;
            }
        } else if (t >= 64 && t < 64 + XB) {
            tau_out[t - 64] = 0.f;
        }
    }
    const int r = t >> 5;
    const int l = t & 31;
    const int row = blockIdx.x * 8 + r;
    float acc = 0.f;
    {
        const float* xr = x + row * 3;
        const float* hr = h + row * 32;
        for (int k = 0; k < 3; ++k)  acc += xr[k] * Wn[k * 32 + l];
        for (int k = 0; k < 32; ++k) acc += hr[k] * Wn[(3 + k) * 32 + l];
    }
    __shared__ float zs[8][32];
    zs[r][l] = acc;
    z[row * 32 + l] = acc;
    __syncthreads();
    float a = 0.f, bb = 0.f;
    for (int k = 0; k < 32; ++k) {
        const float zk = zs[r][k];
        a  += zk * Wm[k * 32 + l];
        bb += zk * Wm[(32 + k) * 32 + l];
    }
    A1[row * 32 + l] = a;
    B1[row * 32 + l] = bb;
}

// ---- m2: mpnn1 — 4 i-rows per block share the B1 j-scan; NaN-masked ev, float4 LDS path ----
__global__ __launch_bounds__(256) void ne2s_m2(
    const int* __restrict__ adj, const float* __restrict__ ef,
    const float* __restrict__ z, const float* __restrict__ A1,
    const float* __restrict__ B1, const float* __restrict__ drv,
    const float* __restrict__ Wu, const float* __restrict__ Wd,
    const float* __restrict__ Wtm, const float* __restrict__ Wp,
    float* __restrict__ A2, float* __restrict__ B2,
    float* __restrict__ hp1, float* __restrict__ hp2,
    float* __restrict__ o_newx, float* __restrict__ o_newh)
{
    const int q = blockIdx.x;                 // 0..511
    const int b = q >> 7;                     // 128 blocks per batch
    const int i0 = (q & 127) * 4;
    const int row0 = b * XN + i0;
    const int t = threadIdx.x;
    const float qnan = __uint_as_float(QNANU);

    __shared__ float ev[4][XN];               // masked: qNaN where !adj && !self
    {
        const int4*   ab4 = (const int4*)  (adj + (size_t)row0 * XN);
        const float4* eb4 = (const float4*)(ef  + (size_t)row0 * XN);
        for (int u = t; u < XN; u += 256) {   // 512 vec4 chunks cover 4 rows
            const int4   a4 = ab4[u];
            float4       e4 = eb4[u];
            const int r  = u >> 7;
            const int j0 = (u & 127) << 2;
            const int self = i0 + r;
            e4.x = (a4.x || (j0 + 0) == self) ? e4.x : qnan;
            e4.y = (a4.y || (j0 + 1) == self) ? e4.y : qnan;
            e4.z = (a4.z || (j0 + 2) == self) ? e4.z : qnan;
            e4.w = (a4.w || (j0 + 3) == self) ? e4.w : qnan;
            *(float4*)&ev[r][j0] = e4;        // 16B-aligned LDS write
        }
    }
    __syncthreads();

    const int c = t >> 5, l = t & 31;
    const float c1 = drv[l];
    const float* B1b = B1 + (size_t)b * XN * 32;
    float m0 = XNEG, m1 = XNEG, m2v = XNEG, m3v = XNEG;
#pragma unroll 2
    for (int k4 = 0; k4 < 16; ++k4) {
        const int j = c * 64 + k4 * 4;
        const float4 e0 = *(const float4*)&ev[0][j];   // ds_read_b128, broadcast addr
        const float4 e1 = *(const float4*)&ev[1][j];
        const float4 e2 = *(const float4*)&ev[2][j];
        const float4 e3 = *(const float4*)&ev[3][j];
        const float bv0 = B1b[(j + 0) * 32 + l];
        const float bv1 = B1b[(j + 1) * 32 + l];
        const float bv2 = B1b[(j + 2) * 32 + l];
        const float bv3 = B1b[(j + 3) * 32 + l];
        // masked ev is NaN -> fma yields NaN -> fmaxf returns old m (IEEE maxNum)
        m0  = fmaxf(fmaxf(m0,  fmaf(e0.x, c1, bv0)), fmaf(e0.y, c1, bv1));
        m0  = fmaxf(fmaxf(m0,  fmaf(e0.z, c1, bv2)), fmaf(e0.w, c1, bv3));
        m1  = fmaxf(fmaxf(m1,  fmaf(e1.x, c1, bv0)), fmaf(e1.y, c1, bv1));
        m1  = fmaxf(fmaxf(m1,  fmaf(e1.z, c1, bv2)), fmaf(e1.w, c1, bv3));
        m2v = fmaxf(fmaxf(m2v, fmaf(e2.x, c1, bv0)), fmaf(e2.y, c1, bv1));
        m2v = fmaxf(fmaxf(m2v, fmaf(e2.z, c1, bv2)), fmaf(e2.w, c1, bv3));
        m3v = fmaxf(fmaxf(m3v, fmaf(e3.x, c1, bv0)), fmaf(e3.y, c1, bv1));
        m3v = fmaxf(fmaxf(m3v, fmaf(e3.z, c1, bv2)), fmaf(e3.w, c1, bv3));
    }
    __shared__ float red[4][8][33];
    red[0][c][l] = m0;  red[1][c][l] = m1;
    red[2][c][l] = m2v; red[3][c][l] = m3v;
    __syncthreads();

    __shared__ float zs[4][32], ag[4][32], nh[4][32];
    if (t < 128) {
        const int r = t >> 5, ll = t & 31;
        float mm = red[r][0][ll];
        for (int cc = 1; cc < 8; ++cc) mm = fmaxf(mm, red[r][cc][ll]);
        ag[r][ll] = A1[(row0 + r) * 32 + ll] + mm;
        zs[r][ll] = z[(row0 + r) * 32 + ll];
    }
    __syncthreads();
    if (t < 128) {
        const int r = t >> 5, ll = t & 31;
        float v = zs[r][ll];                              // residual + z
        for (int k = 0; k < 32; ++k)
            v += zs[r][k] * Wu[k * 32 + ll] + ag[r][k] * Wu[(32 + k) * 32 + ll];
        nh[r][ll] = v;
        o_newh[(row0 + r) * 32 + ll] = v;
    }
    __syncthreads();
    if (t < 128) {
        const int r = t >> 5, ll = t & 31;
        float a2 = 0.f, b2 = 0.f;
        for (int k = 0; k < 32; ++k) {
            const float nk = nh[r][k];
            a2 += nk * Wtm[k * 32 + ll];
            b2 += nk * Wtm[(32 + k) * 32 + ll];
        }
        A2[(row0 + r) * 32 + ll] = a2;
        B2[(row0 + r) * 32 + ll] = b2;
    } else if (t < 136) {                                 // 8 threads: 4 rows x {hp1,hp2}
        const int r = (t - 128) >> 1, which = (t - 128) & 1;
        float p = 0.f;
        for (int k = 0; k < 32; ++k) p += nh[r][k] * Wp[which * 32 + k];
        (which ? hp2 : hp1)[row0 + r] = p;
    } else if (t >= 160 && t < 172) {                     // 12 threads: 4 rows x 3 cols
        const int r = (t - 160) / 3, d = (t - 160) % 3;
        float v = 0.f;
        for (int k = 0; k < 32; ++k)
            v += zs[r][k] * Wd[k * 3 + d] + nh[r][k] * Wd[(32 + k) * 3 + d];
        o_newx[(row0 + r) * 3 + d] = v;
    }
}

// ---- m3: termination scan (4 rows/block) + fused p-head + tau; float4 LDS path ----
__global__ __launch_bounds__(256) void ne2s_m3(
    const int* __restrict__ adj, const float* __restrict__ ef,
    const float* __restrict__ A2, const float* __restrict__ B2,
    const float* __restrict__ newh, const float* __restrict__ hp1,
    const float* __restrict__ hp2, const float* __restrict__ drv,
    float* __restrict__ o_p, float* __restrict__ tau_out)
{
    const int q = blockIdx.x;
    const int b = q >> 7;
    const int i0 = (q & 127) * 4;
    const int row0 = b * XN + i0;
    const int t = threadIdx.x;
    const float qnan = __uint_as_float(QNANU);

    __shared__ float ev[4][XN];               // masked: qNaN where !adj && !self
    {
        const int4*   ab4 = (const int4*)  (adj + (size_t)row0 * XN);
        const float4* eb4 = (const float4*)(ef  + (size_t)row0 * XN);
        for (int u = t; u < XN; u += 256) {
            const int4   a4 = ab4[u];
            float4       e4 = eb4[u];
            const int r  = u >> 7;
            const int j0 = (u & 127) << 2;
            const int self = i0 + r;
            e4.x = (a4.x || (j0 + 0) == self) ? e4.x : qnan;
            e4.y = (a4.y || (j0 + 1) == self) ? e4.y : qnan;
            e4.z = (a4.z || (j0 + 2) == self) ? e4.z : qnan;
            e4.w = (a4.w || (j0 + 3) == self) ? e4.w : qnan;
            *(float4*)&ev[r][j0] = e4;
        }
    }
    __syncthreads();

    // fused predecessor head: masked entries show up as NaN -> map to sentinel (bit test,
    // fast-math-proof). Unmasked values are provably finite -> pass through unchanged.
    {
        const float cp = drv[128];
        const float* h2 = hp2 + b * XN;
#pragma unroll
        for (int r = 0; r < 4; ++r) {
            const float h1 = hp1[row0 + r];
            float* pr = o_p + (size_t)(row0 + r) * XN;
            for (int j = t; j < XN; j += 256) {
                const float pv = fmaf(ev[r][j], cp, h1 + h2[j]);
                const unsigned bv = __float_as_uint(pv);
                pr[j] = ((bv & 0x7f800000u) == 0x7f800000u) ? XSENT : pv;
            }
        }
    }

    const int c = t >> 5, l = t & 31;
    const float c2 = drv[32 + l];
    const float* B2b = B2 + (size_t)b * XN * 32;
    float m0 = XNEG, m1 = XNEG, m2v = XNEG, m3v = XNEG;
#pragma unroll 2
    for (int k4 = 0; k4 < 16; ++k4) {
        const int j = c * 64 + k4 * 4;
        const float4 e0 = *(const float4*)&ev[0][j];
        const float4 e1 = *(const float4*)&ev[1][j];
        const float4 e2 = *(const float4*)&ev[2][j];
        const float4 e3 = *(const float4*)&ev[3][j];
        const float bv0 = B2b[(j + 0) * 32 + l];
        const float bv1 = B2b[(j + 1) * 32 + l];
        const float bv2 = B2b[(j + 2) * 32 + l];
        const float bv3 = B2b[(j + 3) * 32 + l];
        m0  = fmaxf(fmaxf(m0,  fmaf(e0.x, c2, bv0)), fmaf(e0.y, c2, bv1));
        m0  = fmaxf(fmaxf(m0,  fmaf(e0.z, c2, bv2)), fmaf(e0.w, c2, bv3));
        m1  = fmaxf(fmaxf(m1,  fmaf(e1.x, c2, bv0)), fmaf(e1.y, c2, bv1));
        m1  = fmaxf(fmaxf(m1,  fmaf(e1.z, c2, bv2)), fmaf(e1.w, c2, bv3));
        m2v = fmaxf(fmaxf(m2v, fmaf(e2.x, c2, bv0)), fmaf(e2.y, c2, bv1));
        m2v = fmaxf(fmaxf(m2v, fmaf(e2.z, c2, bv2)), fmaf(e2.w, c2, bv3));
        m3v = fmaxf(fmaxf(m3v, fmaf(e3.x, c2, bv0)), fmaf(e3.y, c2, bv1));
        m3v = fmaxf(fmaxf(m3v, fmaf(e3.z, c2, bv2)), fmaf(e3.w, c2, bv3));
    }
    __shared__ float red[4][8][33];
    red[0][c][l] = m0;  red[1][c][l] = m1;
    red[2][c][l] = m2v; red[3][c][l] = m3v;
    __syncthreads();

    __shared__ float ss[4][32];
    if (t < 128) {
        const int r = t >> 5, ll = t & 31;
        float mm = red[r][0][ll];
        for (int cc = 1; cc < 8; ++cc) mm = fmaxf(mm, red[r][cc][ll]);
        const float agg = A2[(row0 + r) * 32 + ll] + mm;
        ss[r][ll] = newh[(row0 + r) * 32 + ll] * drv[64 + ll] + agg * drv[96 + ll];
    }
    __syncthreads();
    if (t < 64) {                              // parallel tau reduce (one wave)
        const float* ssf = &ss[0][0];
        float s = ssf[t] + ssf[t + 64];
#pragma unroll
        for (int o = 32; o > 0; o >>= 1) s += __shfl_down(s, o);
        if (t == 0) atomicAdd(&tau_out[b], s * (1.0f / XN));
    }
}

extern "C" void kernel_launch(void* const* d_in, const int* in_sizes, int n_in,
                              void* d_out, int out_size, void* d_ws, size_t ws_size,
                              hipStream_t stream)
{
    const float* x   = (const float*)d_in[0];
    const float* h   = (const float*)d_in[1];
    const int*   adj = (const int*)  d_in[2];
    const float* ef  = (const float*)d_in[3];
    const float* Wn  = (const float*)d_in[4];
    const float* We  = (const float*)d_in[5];
    const float* Wm  = (const float*)d_in[6];
    const float* Wu  = (const float*)d_in[7];
    const float* Wtm = (const float*)d_in[8];
    const float* Wtu = (const float*)d_in[9];
    const float* Wd  = (const float*)d_in[10];
    const float* Wt  = (const float*)d_in[11];
    const float* Wp  = (const float*)d_in[12];

    float* out    = (float*)d_out;
    float* o_newx = out;                          // [4,512,3]   6144
    float* o_p    = out + 6144;                   // [4,512,512] 1048576
    float* o_tau  = out + 6144 + XB * XN * XN;    // [4,1]       4
    float* o_newh = o_tau + XB;                   // [4,512,32]  65536

    float* w = (float*)d_ws;
    const int RN = XB * XN * 32;                  // 65536
    float* z   = w;
    float* A1  = w + RN;
    float* B1  = w + 2 * RN;
    float* A2  = w + 3 * RN;
    float* B2  = w + 4 * RN;
    float* hp1 = w + 5 * RN;
    float* hp2 = w + 5 * RN + XB * XN;
    float* drv = w + 5 * RN + 2 * XB * XN;

    hipLaunchKernelGGL(ne2s_g1, dim3(XB * XN / 8), dim3(256), 0, stream,
                       x, h, Wn, Wm, We, Wtm, Wtu, Wt, Wp, z, A1, B1, drv, o_tau);
    hipLaunchKernelGGL(ne2s_m2, dim3(XB * XN / 4), dim3(256), 0, stream,
                       adj, ef, z, A1, B1, drv, Wu, Wd, Wtm, Wp,
                       A2, B2, hp1, hp2, o_newx, o_newh);
    hipLaunchKernelGGL(ne2s_m3, dim3(XB * XN / 4), dim3(256), 0, stream,
                       adj, ef, A2, B2, o_newh, hp1, hp2, drv, o_p, o_tau);
}